// Round 12
// baseline (185.871 us; speedup 1.0000x reference)
//
#include <hip/hip_runtime.h>

#define HID 64
#define TT  128
#define NROWS 8192
#define NGRP 512            // 512 blocks; each handles 2 groups of 8 rows
#define LOG2E 1.44269504088896f

typedef _Float16 half8 __attribute__((ext_vector_type(8)));
typedef float    f32x4 __attribute__((ext_vector_type(4)));

// ---------- pre-pass: length-sort rows into 8-row groups ----------
// ws layout (ints): lens[8192] | perm[8192]

__global__ void k_len(const int* __restrict__ mask, int* __restrict__ lens) {
    const int row = blockIdx.x * 4 + (threadIdx.x >> 6);
    const int l   = threadIdx.x & 63;
    const int* mrow = mask + row * TT;
    int c = (mrow[l] != 0) + (mrow[l + 64] != 0);
    #pragma unroll
    for (int k = 32; k >= 1; k >>= 1) c += __shfl_xor(c, k);
    if (l == 0) lens[row] = c;
}

// Descending rank d -> group g8 = d/8. Adjacent (equal-length) groups pair
// into one block: block b = g8>>1, slot s = g8&1. perm layout [512][2][8].
__global__ __launch_bounds__(1024) void k_sort(const int* __restrict__ lens,
                                               int* __restrict__ perm) {
    __shared__ int hist[TT + 1];
    __shared__ int offs[TT + 1];
    const int tid = threadIdx.x;
    if (tid <= TT) hist[tid] = 0;
    __syncthreads();
    int myL[8];
    #pragma unroll
    for (int i = 0; i < 8; i++) {
        myL[i] = lens[tid + 1024 * i];
        atomicAdd(&hist[myL[i]], 1);
    }
    __syncthreads();
    if (tid <= TT) {
        int s = 0;
        for (int j = 0; j < tid; j++) s += hist[j];
        offs[tid] = s;
    }
    __syncthreads();
    #pragma unroll
    for (int i = 0; i < 8; i++) {
        const int pos = atomicAdd(&offs[myL[i]], 1);      // ascending rank
        const int d   = NROWS - 1 - pos;                  // descending rank
        const int g8  = d >> 3, r = d & 7;
        perm[((g8 >> 1) * 2 + (g8 & 1)) * 8 + r] = tid + 1024 * i;
    }
}

// ---------- main GRU: two interleaved 8-row recurrences per block ----------
// Per group: cols 0-7 rows / 8-15 dups; lane hf=cc>>3 activates e-pair.
// Program-order interleave G0/G1 hides each chain under the other's issue.
__global__ __launch_bounds__(256, 2) void gru_fused(
    const int* __restrict__ actor_ids, const int* __restrict__ action_ids,
    const int* __restrict__ street_ids, const float* __restrict__ bet,
    const float* __restrict__ E_actor, const float* __restrict__ E_action,
    const float* __restrict__ E_street, const float* __restrict__ W_proj,
    const float* __restrict__ b_proj, const float* __restrict__ W_ih,
    const float* __restrict__ b_ih, const float* __restrict__ W_hh,
    const float* __restrict__ b_hh, const int* __restrict__ perm,
    const int* __restrict__ lens, float* __restrict__ out)
{
    __shared__ __align__(16) union {
        float wfs[192][32];                           // startup: fused W_f (scaled)
        struct {
            int pb[2][TT][9];                         // per-group ids|bet16
            __align__(16) _Float16 hb[2][2][8][72];   // [group][buf][row][72]
            int Lsh[2][8];
            int Psh[2][8];
        } c;
    } A;
    __shared__ __align__(16) _Float16 embl[8][136];   // 8 bank-offset copies
    __shared__ float bfs[192];                        // raw fused bias b_f

    const int tid = threadIdx.x;
    const int wv  = tid >> 6;        // wave = hid quarter (j-split)
    const int l   = tid & 63;
    const int q   = l >> 4;          // k-quad / j-subquad
    const int cc  = l & 15;          // MFMA col
    const int cr  = cc & 7;          // batch row within group
    const int hf  = cc >> 3;         // activation element half
    const int g   = blockIdx.x;
    const int ec  = l & 7;           // embl copy for this lane

    // embedding rows: 0..6 actor, 7..10 action, 11..15 street(+pad), 16 zero
    for (int i = tid; i < 136; i += 256) {
        int r = i >> 3, m = i & 7;
        float v = 0.f;
        if (r < 7)       v = E_actor[r * 8 + m];
        else if (r < 11) v = E_action[(r - 7) * 8 + m];
        else if (r < 16) v = (m < 4) ? E_street[(r - 11) * 4 + m] : 0.f;
        const _Float16 hv = (_Float16)v;
        #pragma unroll
        for (int c8 = 0; c8 < 8; c8++) embl[c8][i] = hv;
    }

    // ---- startup: fused input weights into LDS ----
    if (tid < 192) {
        const int j = tid;
        float wf[21];
        #pragma unroll
        for (int m = 0; m < 21; m++) wf[m] = 0.f;
        float bf = b_ih[j];
        for (int k = 0; k < 32; k++) {
            const float w = W_ih[j * 32 + k];
            bf += w * b_proj[k];
            #pragma unroll
            for (int m = 0; m < 21; m++) wf[m] += w * W_proj[k * 21 + m];
        }
        const float s = (j < 128) ? LOG2E : 2.f * LOG2E;
        #pragma unroll
        for (int m = 0; m < 21; m++) A.wfs[j][m] = wf[m] * s;
        #pragma unroll
        for (int m = 21; m < 32; m++) A.wfs[j][m] = 0.f;
        bfs[j] = bf;
    }
    __syncthreads();

    // ---- extract per-lane A-fragments + biases (shared by both groups) ----
    half8 Af[3], Ah[3][2];
    {
        const int m16 = l & 15, kq = l >> 4;
        #pragma unroll
        for (int g3 = 0; g3 < 3; g3++) {
            const int jr = g3 * 64 + wv * 16 + m16;
            _Float16 v[8];
            #pragma unroll
            for (int m = 0; m < 8; m++) v[m] = (_Float16)A.wfs[jr][kq * 8 + m];
            Af[g3] = *(half8*)v;
            const float s = (g3 < 2) ? LOG2E : 2.f * LOG2E;
            #pragma unroll
            for (int kt = 0; kt < 2; kt++) {
                _Float16 w[8];
                #pragma unroll
                for (int m = 0; m < 8; m++)
                    w[m] = (_Float16)(W_hh[jr * HID + kt * 32 + kq * 8 + m] * s);
                Ah[g3][kt] = *(half8*)w;
            }
        }
    }
    f32x4 biasR, biasZ, biasX, biasH;
    #pragma unroll
    for (int e = 0; e < 4; e++) {
        const int idx = 16 * wv + 4 * q + e;
        biasR[e] = (bfs[idx]      + b_hh[idx])      * LOG2E;
        biasZ[e] = (bfs[64 + idx] + b_hh[64 + idx]) * LOG2E;
        biasX[e] = bfs[128 + idx]  * (2.f * LOG2E);
        biasH[e] = b_hh[128 + idx] * (2.f * LOG2E);
    }
    __syncthreads();   // wfs dead; arena becomes pb/hb

    // ---- stage both groups' pb (16 thr/row), zero hb, fetch lengths ----
    for (int i = tid; i < 2 * 2 * 8 * 72 / 2; i += 256) ((int*)A.c.hb)[i] = 0;
    {
        const int r16 = tid >> 4, tl = tid & 15;     // r16: 0..15 (group = r16>>3)
        const int gi = r16 >> 3, r = r16 & 7;
        const int prow = perm[(g * 2 + gi) * 8 + r];
        const int base = prow * TT;
        #pragma unroll
        for (int i = 0; i < 8; i++) {
            const int t = tl + 16 * i;
            const int a = actor_ids[base + t], c = action_ids[base + t];
            const int s = street_ids[base + t];
            const _Float16 f16 = (_Float16)bet[base + t];
            const unsigned fb = (unsigned)*(const unsigned short*)&f16;
            A.c.pb[gi][t][r] = (int)(a | (c << 3) | (s << 5) | (fb << 16));
        }
        if (tl == 0) { A.c.Lsh[gi][r] = lens[prow]; A.c.Psh[gi][r] = prow; }
    }
    __syncthreads();

    int Ln[2];
    Ln[0] = A.c.Lsh[0][cr];
    Ln[1] = A.c.Lsh[1][cr];
    int Lmax = Ln[0] > Ln[1] ? Ln[0] : Ln[1];
    { int o = __shfl_xor(Lmax, 1); Lmax = o > Lmax ? o : Lmax; }
    { int o = __shfl_xor(Lmax, 2); Lmax = o > Lmax ? o : Lmax; }
    { int o = __shfl_xor(Lmax, 4); Lmax = o > Lmax ? o : Lmax; }

    const bool isq2 = (q == 2);
    const int sh = (q == 1) ? 3 : (q == 2) ? 5 : 0;
    const int mk = (q == 1) ? 3 : (q == 3) ? 0 : 7;
    const int of = (q == 1) ? 7 : (q == 2) ? 11 : (q == 3) ? 16 : 0;

    const int j0 = 16 * wv + 4 * q + 2 * hf;
    float h0[2] = {0.f, 0.f}, h1[2] = {0.f, 0.f};
    const f32x4 zero4 = {0.f, 0.f, 0.f, 0.f};

    // ---- prologue per group: Bf(0), Bf(1); x(0) ----
    half8 BfA[2], BfB[2];
    f32x4 xR0[2], xZ0[2], xX0[2], xR1[2], xZ1[2], xX1[2];
    #pragma unroll
    for (int gi = 0; gi < 2; gi++) {
        const int p0 = A.c.pb[gi][0][cr];
        BfA[gi] = *(const half8*)&embl[ec][(((p0 >> sh) & mk) + of) * 8];
        uint4* b0 = (uint4*)&BfA[gi];
        b0->z = isq2 ? ((unsigned)p0 >> 16) : b0->z;   // {bet16, 0} at k=20,21
        const int p1 = A.c.pb[gi][1][cr];
        BfB[gi] = *(const half8*)&embl[ec][(((p1 >> sh) & mk) + of) * 8];
        uint4* b1 = (uint4*)&BfB[gi];
        b1->z = isq2 ? ((unsigned)p1 >> 16) : b1->z;
        xR0[gi] = __builtin_amdgcn_mfma_f32_16x16x32_f16(Af[0], BfA[gi], biasR, 0, 0, 0);
        xZ0[gi] = __builtin_amdgcn_mfma_f32_16x16x32_f16(Af[1], BfA[gi], biasZ, 0, 0, 0);
        xX0[gi] = __builtin_amdgcn_mfma_f32_16x16x32_f16(Af[2], BfA[gi], biasX, 0, 0, 0);
    }

    // per-group step body: reads hb[gi][RB], writes hb[gi][WB]
    #define STEP_G(gi_, RB_, WB_, xR_, xZ_, xX_, xRn_, xZn_, xXn_, BfC_, BfN_, TOFF_) \
    {                                                                              \
        const half8 Bh0 = *(const half8*)&A.c.hb[gi_][RB_][cr][q * 8];             \
        const half8 Bh1 = *(const half8*)&A.c.hb[gi_][RB_][cr][32 + q * 8];        \
        const int tn = (t + (TOFF_) < TT) ? t + (TOFF_) : TT - 1;                  \
        const int pn = A.c.pb[gi_][tn][cr];                                        \
        f32x4 aRa = __builtin_amdgcn_mfma_f32_16x16x32_f16(Ah[0][0], Bh0, xR_[gi_], 0, 0, 0); \
        f32x4 aRb = __builtin_amdgcn_mfma_f32_16x16x32_f16(Ah[0][1], Bh1, zero4, 0, 0, 0);    \
        f32x4 aZ = __builtin_amdgcn_mfma_f32_16x16x32_f16(Ah[1][0], Bh0, xZ_[gi_], 0, 0, 0);  \
        aZ = __builtin_amdgcn_mfma_f32_16x16x32_f16(Ah[1][1], Bh1, aZ, 0, 0, 0);   \
        f32x4 aH = __builtin_amdgcn_mfma_f32_16x16x32_f16(Ah[2][0], Bh0, biasH, 0, 0, 0);     \
        aH = __builtin_amdgcn_mfma_f32_16x16x32_f16(Ah[2][1], Bh1, aH, 0, 0, 0);   \
        const f32x4 aR = aRa + aRb;                                                \
        xRn_[gi_] = __builtin_amdgcn_mfma_f32_16x16x32_f16(Af[0], BfN_[gi_], biasR, 0, 0, 0); \
        xZn_[gi_] = __builtin_amdgcn_mfma_f32_16x16x32_f16(Af[1], BfN_[gi_], biasZ, 0, 0, 0); \
        xXn_[gi_] = __builtin_amdgcn_mfma_f32_16x16x32_f16(Af[2], BfN_[gi_], biasX, 0, 0, 0); \
        BfC_[gi_] = *(const half8*)&embl[ec][(((pn >> sh) & mk) + of) * 8];        \
        uint4* bq = (uint4*)&BfC_[gi_];                                            \
        bq->z = isq2 ? ((unsigned)pn >> 16) : bq->z;                               \
        const f32x4 aX = xX_[gi_];                                                 \
        const float vR0 = hf ? aR[2] : aR[0], vR1 = hf ? aR[3] : aR[1];            \
        const float vZ0 = hf ? aZ[2] : aZ[0], vZ1 = hf ? aZ[3] : aZ[1];            \
        const float vH0 = hf ? aH[2] : aH[0], vH1 = hf ? aH[3] : aH[1];            \
        const float vX0 = hf ? aX[2] : aX[0], vX1 = hf ? aX[3] : aX[1];            \
        const bool live = (t + ((TOFF_) - 2) < Ln[gi_]);                           \
        const float r0 = __builtin_amdgcn_rcpf(1.f + __builtin_amdgcn_exp2f(-vR0));\
        const float z0 = __builtin_amdgcn_rcpf(1.f + __builtin_amdgcn_exp2f(-vZ0));\
        const float y0 = vX0 + r0 * vH0;                                           \
        const float n0 = 1.f - 2.f * __builtin_amdgcn_rcpf(1.f + __builtin_amdgcn_exp2f(y0)); \
        const float hv0 = n0 + z0 * (h0[gi_] - n0);                                \
        h0[gi_] = live ? hv0 : h0[gi_];                                            \
        const float r1 = __builtin_amdgcn_rcpf(1.f + __builtin_amdgcn_exp2f(-vR1));\
        const float z1 = __builtin_amdgcn_rcpf(1.f + __builtin_amdgcn_exp2f(-vZ1));\
        const float y1 = vX1 + r1 * vH1;                                           \
        const float n1 = 1.f - 2.f * __builtin_amdgcn_rcpf(1.f + __builtin_amdgcn_exp2f(y1)); \
        const float hv1 = n1 + z1 * (h1[gi_] - n1);                                \
        h1[gi_] = live ? hv1 : h1[gi_];                                            \
        const _Float16 a16 = (_Float16)h0[gi_], b16 = (_Float16)h1[gi_];           \
        const unsigned pk = (unsigned)*(const unsigned short*)&a16 |               \
                            ((unsigned)*(const unsigned short*)&b16 << 16);        \
        *(unsigned*)&A.c.hb[gi_][WB_][cr][j0] = pk;                                \
    }

    for (int t = 0; t < Lmax; t += 2) {
        // step A (even t): read buf0, write buf1; TOFF=2 -> gathers Bf(t+2), live t
        STEP_G(0, 0, 1, xR0, xZ0, xX0, xR1, xZ1, xX1, BfA, BfB, 2);
        STEP_G(1, 0, 1, xR0, xZ0, xX0, xR1, xZ1, xX1, BfA, BfB, 2);
        __syncthreads();
        // step B (t+1): read buf1, write buf0; TOFF=3 -> gathers Bf(t+3), live t+1
        STEP_G(0, 1, 0, xR1, xZ1, xX1, xR0, xZ0, xX0, BfB, BfA, 3);
        STEP_G(1, 1, 0, xR1, xZ1, xX1, xR0, xZ0, xX0, BfB, BfA, 3);
        __syncthreads();
    }
    #undef STEP_G

    #pragma unroll
    for (int gi = 0; gi < 2; gi++) {
        const int prow = A.c.Psh[gi][cr];
        *(float2*)&out[prow * HID + j0] = make_float2(h0[gi], h1[gi]);
    }
}

extern "C" void kernel_launch(void* const* d_in, const int* in_sizes, int n_in,
                              void* d_out, int out_size, void* d_ws, size_t ws_size,
                              hipStream_t stream) {
    const int*   actor_ids  = (const int*)d_in[0];
    const int*   action_ids = (const int*)d_in[1];
    const int*   street_ids = (const int*)d_in[2];
    const float* bet        = (const float*)d_in[3];
    const int*   vmask      = (const int*)d_in[4];
    const float* E_actor    = (const float*)d_in[5];
    const float* E_action   = (const float*)d_in[6];
    const float* E_street   = (const float*)d_in[7];
    const float* W_proj     = (const float*)d_in[8];
    const float* b_proj     = (const float*)d_in[9];
    const float* W_ih       = (const float*)d_in[10];
    const float* W_hh       = (const float*)d_in[11];
    const float* b_ih       = (const float*)d_in[12];
    const float* b_hh       = (const float*)d_in[13];
    float*       out        = (float*)d_out;

    int* ws   = (int*)d_ws;
    int* lens = ws;
    int* perm = ws + NROWS;

    k_len<<<NROWS / 4, 256, 0, stream>>>(vmask, lens);
    k_sort<<<1, 1024, 0, stream>>>(lens, perm);

    gru_fused<<<NGRP, 256, 0, stream>>>(actor_ids, action_ids, street_ids, bet,
                                        E_actor, E_action, E_street,
                                        W_proj, b_proj, W_ih, b_ih, W_hh, b_hh,
                                        perm, lens, out);
}

// Round 13
// 157.328 us; speedup vs baseline: 1.1814x; 1.1814x over previous
//
#include <hip/hip_runtime.h>

#define HID 64
#define TT  128
#define NROWS 8192
#define NGRP (NROWS / 8)    // 1024 blocks of 8 rows; 4 blocks/CU
#define LOG2E 1.44269504088896f

typedef _Float16 half8 __attribute__((ext_vector_type(8)));
typedef float    f32x4 __attribute__((ext_vector_type(4)));

// ---------- pre-pass: length-sort rows into balanced 8-row groups ----------
// ws layout (ints): lens[8192] | perm[8192]

__global__ void k_len(const int* __restrict__ mask, int* __restrict__ lens) {
    const int row = blockIdx.x * 4 + (threadIdx.x >> 6);
    const int l   = threadIdx.x & 63;
    const int* mrow = mask + row * TT;
    int c = (mrow[l] != 0) + (mrow[l + 64] != 0);
    #pragma unroll
    for (int k = 32; k >= 1; k >>= 1) c += __shfl_xor(c, k);
    if (l == 0) lens[row] = c;
}

// Single block: LDS histogram -> prefix -> scatter. Descending rank d ->
// 8-row group g8 = d/8; slots {c, 511-c, 512+c, 1023-c} land on CU c.
__global__ __launch_bounds__(1024) void k_sort(const int* __restrict__ lens,
                                               int* __restrict__ perm) {
    __shared__ int hist[TT + 1];
    __shared__ int offs[TT + 1];
    const int tid = threadIdx.x;
    if (tid <= TT) hist[tid] = 0;
    __syncthreads();
    int myL[8];
    #pragma unroll
    for (int i = 0; i < 8; i++) {
        myL[i] = lens[tid + 1024 * i];
        atomicAdd(&hist[myL[i]], 1);
    }
    __syncthreads();
    if (tid <= TT) {
        int s = 0;
        for (int j = 0; j < tid; j++) s += hist[j];
        offs[tid] = s;
    }
    __syncthreads();
    #pragma unroll
    for (int i = 0; i < 8; i++) {
        const int pos = atomicAdd(&offs[myL[i]], 1);      // ascending rank
        const int d   = NROWS - 1 - pos;                  // descending rank
        const int g8  = d >> 3, r = d & 7;
        int b;
        if      (g8 < 256) b = g8;
        else if (g8 < 512) b = 256 + (511 - g8);
        else if (g8 < 768) b = 512 + (g8 - 512);
        else               b = 768 + (1023 - g8);
        perm[b * 8 + r] = tid + 1024 * i;
    }
}

// ---------- main GRU: R7 structure + 2x unroll + bank-replicated embl ----------
// 8-row blocks, cols 0-7 rows / 8-15 dups; lane hf=cc>>3 activates e-pair.
__global__ __launch_bounds__(256, 4) void gru_fused(
    const int* __restrict__ actor_ids, const int* __restrict__ action_ids,
    const int* __restrict__ street_ids, const float* __restrict__ bet,
    const float* __restrict__ E_actor, const float* __restrict__ E_action,
    const float* __restrict__ E_street, const float* __restrict__ W_proj,
    const float* __restrict__ b_proj, const float* __restrict__ W_ih,
    const float* __restrict__ b_ih, const float* __restrict__ W_hh,
    const float* __restrict__ b_hh, const int* __restrict__ perm,
    const int* __restrict__ lens, float* __restrict__ out)
{
    __shared__ __align__(16) union {
        float wfs[192][32];                           // startup: fused W_f (scaled)
        struct {
            int pb[TT][9];                            // ids|bet16, 8 rows + pad
            __align__(16) _Float16 hb[2][8][72];      // h f16 dbuf, stride 72
            int Lsh[8];
            int Psh[8];
        } c;
    } A;
    // 8 bank-quad-offset copies (copy stride 272B -> base quad = c mod 8):
    // lane uses copy l&7 so the data-dependent gather is conflict-free.
    __shared__ __align__(16) _Float16 embl[8][136];
    __shared__ float bfs[192];                        // raw fused bias b_f

    const int tid = threadIdx.x;
    const int wv  = tid >> 6;        // wave = hid quarter (j-split)
    const int l   = tid & 63;
    const int q   = l >> 4;          // k-quad / j-subquad
    const int cc  = l & 15;          // MFMA col
    const int cr  = cc & 7;          // batch row within group
    const int hf  = cc >> 3;         // activation element half
    const int g   = blockIdx.x;
    const int ec  = l & 7;           // embl copy for this lane

    // embedding rows: 0..6 actor, 7..10 action, 11..15 street(+pad), 16 zero
    for (int i = tid; i < 136; i += 256) {
        int r = i >> 3, m = i & 7;
        float v = 0.f;
        if (r < 7)       v = E_actor[r * 8 + m];
        else if (r < 11) v = E_action[(r - 7) * 8 + m];
        else if (r < 16) v = (m < 4) ? E_street[(r - 11) * 4 + m] : 0.f;
        const _Float16 hv = (_Float16)v;
        #pragma unroll
        for (int c8 = 0; c8 < 8; c8++) embl[c8][i] = hv;
    }

    // ---- startup: fused input weights into LDS ----
    if (tid < 192) {
        const int j = tid;
        float wf[21];
        #pragma unroll
        for (int m = 0; m < 21; m++) wf[m] = 0.f;
        float bf = b_ih[j];
        for (int k = 0; k < 32; k++) {
            const float w = W_ih[j * 32 + k];
            bf += w * b_proj[k];
            #pragma unroll
            for (int m = 0; m < 21; m++) wf[m] += w * W_proj[k * 21 + m];
        }
        const float s = (j < 128) ? LOG2E : 2.f * LOG2E;
        #pragma unroll
        for (int m = 0; m < 21; m++) A.wfs[j][m] = wf[m] * s;
        #pragma unroll
        for (int m = 21; m < 32; m++) A.wfs[j][m] = 0.f;
        bfs[j] = bf;
    }
    __syncthreads();

    // ---- extract per-lane A-fragments + biases (registers) ----
    half8 Af[3], Ah[3][2];
    {
        const int m16 = l & 15, kq = l >> 4;
        #pragma unroll
        for (int g3 = 0; g3 < 3; g3++) {
            const int jr = g3 * 64 + wv * 16 + m16;
            _Float16 v[8];
            #pragma unroll
            for (int m = 0; m < 8; m++) v[m] = (_Float16)A.wfs[jr][kq * 8 + m];
            Af[g3] = *(half8*)v;
            const float s = (g3 < 2) ? LOG2E : 2.f * LOG2E;
            #pragma unroll
            for (int kt = 0; kt < 2; kt++) {
                _Float16 w[8];
                #pragma unroll
                for (int m = 0; m < 8; m++)
                    w[m] = (_Float16)(W_hh[jr * HID + kt * 32 + kq * 8 + m] * s);
                Ah[g3][kt] = *(half8*)w;
            }
        }
    }
    f32x4 biasR, biasZ, biasX, biasH;
    #pragma unroll
    for (int e = 0; e < 4; e++) {
        const int idx = 16 * wv + 4 * q + e;
        biasR[e] = (bfs[idx]      + b_hh[idx])      * LOG2E;
        biasZ[e] = (bfs[64 + idx] + b_hh[64 + idx]) * LOG2E;
        biasX[e] = bfs[128 + idx]  * (2.f * LOG2E);
        biasH[e] = b_hh[128 + idx] * (2.f * LOG2E);
    }
    __syncthreads();   // wfs dead; arena becomes pb/hb

    // ---- stage pb via perm (32 thr/row), zero hb, fetch lengths ----
    for (int i = tid; i < 2 * 8 * 72 / 2; i += 256) ((int*)A.c.hb)[i] = 0;
    {
        const int r = tid >> 5, tl = tid & 31;
        const int prow = perm[g * 8 + r];
        const int base = prow * TT;
        #pragma unroll
        for (int i = 0; i < 4; i++) {
            const int t = tl + 32 * i;
            const int a = actor_ids[base + t], c = action_ids[base + t];
            const int s = street_ids[base + t];
            const _Float16 f16 = (_Float16)bet[base + t];
            const unsigned fb = (unsigned)*(const unsigned short*)&f16;
            A.c.pb[t][r] = (int)(a | (c << 3) | (s << 5) | (fb << 16));
        }
        if (tl == 0) { A.c.Lsh[r] = lens[prow]; A.c.Psh[r] = prow; }
    }
    __syncthreads();

    const int Ln = A.c.Lsh[cr];
    int Lmax = Ln;
    { int o = __shfl_xor(Lmax, 1); Lmax = o > Lmax ? o : Lmax; }
    { int o = __shfl_xor(Lmax, 2); Lmax = o > Lmax ? o : Lmax; }
    { int o = __shfl_xor(Lmax, 4); Lmax = o > Lmax ? o : Lmax; }

    const bool isq2 = (q == 2);
    const int sh = (q == 1) ? 3 : (q == 2) ? 5 : 0;
    const int mk = (q == 1) ? 3 : (q == 3) ? 0 : 7;
    const int of = (q == 1) ? 7 : (q == 2) ? 11 : (q == 3) ? 16 : 0;

    const int j0 = 16 * wv + 4 * q + 2 * hf;
    float h0 = 0.f, h1 = 0.f;
    const f32x4 zero4 = {0.f, 0.f, 0.f, 0.f};

    // ---- prologue: Bf(0), Bf(1); x(0) ----
    half8 BfA, BfB;
    {
        const int p0 = A.c.pb[0][cr];
        BfA = *(const half8*)&embl[ec][(((p0 >> sh) & mk) + of) * 8];
        uint4* b0 = (uint4*)&BfA;
        b0->z = isq2 ? ((unsigned)p0 >> 16) : b0->z;   // {bet16, 0} at k=20,21
        const int p1 = A.c.pb[1][cr];
        BfB = *(const half8*)&embl[ec][(((p1 >> sh) & mk) + of) * 8];
        uint4* b1 = (uint4*)&BfB;
        b1->z = isq2 ? ((unsigned)p1 >> 16) : b1->z;
    }
    f32x4 xR0 = __builtin_amdgcn_mfma_f32_16x16x32_f16(Af[0], BfA, biasR, 0, 0, 0);
    f32x4 xZ0 = __builtin_amdgcn_mfma_f32_16x16x32_f16(Af[1], BfA, biasZ, 0, 0, 0);
    f32x4 xX0 = __builtin_amdgcn_mfma_f32_16x16x32_f16(Af[2], BfA, biasX, 0, 0, 0);
    f32x4 xR1, xZ1, xX1;

    // activation macro: consumes aR,aZ,aH,aX; updates h0,h1; writes hb[WB]
    #define ACT_WRITE(aR_, aZ_, aH_, aX_, LIVE_, WB_)                              \
    {                                                                              \
        const float vR0 = hf ? aR_[2] : aR_[0], vR1 = hf ? aR_[3] : aR_[1];        \
        const float vZ0 = hf ? aZ_[2] : aZ_[0], vZ1 = hf ? aZ_[3] : aZ_[1];        \
        const float vH0 = hf ? aH_[2] : aH_[0], vH1 = hf ? aH_[3] : aH_[1];        \
        const float vX0 = hf ? aX_[2] : aX_[0], vX1 = hf ? aX_[3] : aX_[1];        \
        const float r0 = __builtin_amdgcn_rcpf(1.f + __builtin_amdgcn_exp2f(-vR0));\
        const float z0 = __builtin_amdgcn_rcpf(1.f + __builtin_amdgcn_exp2f(-vZ0));\
        const float y0 = vX0 + r0 * vH0;                                           \
        const float n0 = 1.f - 2.f * __builtin_amdgcn_rcpf(1.f + __builtin_amdgcn_exp2f(y0)); \
        const float hv0 = n0 + z0 * (h0 - n0);                                     \
        h0 = (LIVE_) ? hv0 : h0;                                                   \
        const float r1 = __builtin_amdgcn_rcpf(1.f + __builtin_amdgcn_exp2f(-vR1));\
        const float z1 = __builtin_amdgcn_rcpf(1.f + __builtin_amdgcn_exp2f(-vZ1));\
        const float y1 = vX1 + r1 * vH1;                                           \
        const float n1 = 1.f - 2.f * __builtin_amdgcn_rcpf(1.f + __builtin_amdgcn_exp2f(y1)); \
        const float hv1 = n1 + z1 * (h1 - n1);                                     \
        h1 = (LIVE_) ? hv1 : h1;                                                   \
        const _Float16 a16 = (_Float16)h0, b16 = (_Float16)h1;                     \
        const unsigned pk = (unsigned)*(const unsigned short*)&a16 |               \
                            ((unsigned)*(const unsigned short*)&b16 << 16);        \
        *(unsigned*)&A.c.hb[WB_][cr][j0] = pk;                                     \
    }

    for (int t = 0; t < Lmax; t += 2) {
        // ======== step A (even t): read hb[0], write hb[1] ========
        {
            const half8 Bh0 = *(const half8*)&A.c.hb[0][cr][q * 8];
            const half8 Bh1 = *(const half8*)&A.c.hb[0][cr][32 + q * 8];
            const int t2 = (t + 2 < TT) ? t + 2 : TT - 1;
            const int p2 = A.c.pb[t2][cr];

            f32x4 aRa = __builtin_amdgcn_mfma_f32_16x16x32_f16(Ah[0][0], Bh0, xR0, 0, 0, 0);
            f32x4 aRb = __builtin_amdgcn_mfma_f32_16x16x32_f16(Ah[0][1], Bh1, zero4, 0, 0, 0);
            f32x4 aZ = __builtin_amdgcn_mfma_f32_16x16x32_f16(Ah[1][0], Bh0, xZ0, 0, 0, 0);
            aZ = __builtin_amdgcn_mfma_f32_16x16x32_f16(Ah[1][1], Bh1, aZ, 0, 0, 0);
            f32x4 aH = __builtin_amdgcn_mfma_f32_16x16x32_f16(Ah[2][0], Bh0, biasH, 0, 0, 0);
            aH = __builtin_amdgcn_mfma_f32_16x16x32_f16(Ah[2][1], Bh1, aH, 0, 0, 0);
            const f32x4 aR = aRa + aRb;

            // x(t+1) from BfB (register-only B)
            xR1 = __builtin_amdgcn_mfma_f32_16x16x32_f16(Af[0], BfB, biasR, 0, 0, 0);
            xZ1 = __builtin_amdgcn_mfma_f32_16x16x32_f16(Af[1], BfB, biasZ, 0, 0, 0);
            xX1 = __builtin_amdgcn_mfma_f32_16x16x32_f16(Af[2], BfB, biasX, 0, 0, 0);

            // gather Bf(t+2) -> BfA (old BfA already consumed)
            BfA = *(const half8*)&embl[ec][(((p2 >> sh) & mk) + of) * 8];
            uint4* bq = (uint4*)&BfA;
            bq->z = isq2 ? ((unsigned)p2 >> 16) : bq->z;

            ACT_WRITE(aR, aZ, aH, xX0, t < Ln, 1);
        }
        __syncthreads();
        // ======== step B (t+1): read hb[1], write hb[0] ========
        {
            const half8 Bh0 = *(const half8*)&A.c.hb[1][cr][q * 8];
            const half8 Bh1 = *(const half8*)&A.c.hb[1][cr][32 + q * 8];
            const int t3 = (t + 3 < TT) ? t + 3 : TT - 1;
            const int p3 = A.c.pb[t3][cr];

            f32x4 aRa = __builtin_amdgcn_mfma_f32_16x16x32_f16(Ah[0][0], Bh0, xR1, 0, 0, 0);
            f32x4 aRb = __builtin_amdgcn_mfma_f32_16x16x32_f16(Ah[0][1], Bh1, zero4, 0, 0, 0);
            f32x4 aZ = __builtin_amdgcn_mfma_f32_16x16x32_f16(Ah[1][0], Bh0, xZ1, 0, 0, 0);
            aZ = __builtin_amdgcn_mfma_f32_16x16x32_f16(Ah[1][1], Bh1, aZ, 0, 0, 0);
            f32x4 aH = __builtin_amdgcn_mfma_f32_16x16x32_f16(Ah[2][0], Bh0, biasH, 0, 0, 0);
            aH = __builtin_amdgcn_mfma_f32_16x16x32_f16(Ah[2][1], Bh1, aH, 0, 0, 0);
            const f32x4 aR = aRa + aRb;

            // x(t+2) from BfA (just gathered)
            xR0 = __builtin_amdgcn_mfma_f32_16x16x32_f16(Af[0], BfA, biasR, 0, 0, 0);
            xZ0 = __builtin_amdgcn_mfma_f32_16x16x32_f16(Af[1], BfA, biasZ, 0, 0, 0);
            xX0 = __builtin_amdgcn_mfma_f32_16x16x32_f16(Af[2], BfA, biasX, 0, 0, 0);

            // gather Bf(t+3) -> BfB
            BfB = *(const half8*)&embl[ec][(((p3 >> sh) & mk) + of) * 8];
            uint4* bq = (uint4*)&BfB;
            bq->z = isq2 ? ((unsigned)p3 >> 16) : bq->z;

            ACT_WRITE(aR, aZ, aH, xX1, t + 1 < Ln, 0);
        }
        __syncthreads();
    }
    #undef ACT_WRITE

    const int prow = A.c.Psh[cr];
    *(float2*)&out[prow * HID + j0] = make_float2(h0, h1);
}

extern "C" void kernel_launch(void* const* d_in, const int* in_sizes, int n_in,
                              void* d_out, int out_size, void* d_ws, size_t ws_size,
                              hipStream_t stream) {
    const int*   actor_ids  = (const int*)d_in[0];
    const int*   action_ids = (const int*)d_in[1];
    const int*   street_ids = (const int*)d_in[2];
    const float* bet        = (const float*)d_in[3];
    const int*   vmask      = (const int*)d_in[4];
    const float* E_actor    = (const float*)d_in[5];
    const float* E_action   = (const float*)d_in[6];
    const float* E_street   = (const float*)d_in[7];
    const float* W_proj     = (const float*)d_in[8];
    const float* b_proj     = (const float*)d_in[9];
    const float* W_ih       = (const float*)d_in[10];
    const float* W_hh       = (const float*)d_in[11];
    const float* b_ih       = (const float*)d_in[12];
    const float* b_hh       = (const float*)d_in[13];
    float*       out        = (float*)d_out;

    int* ws   = (int*)d_ws;
    int* lens = ws;
    int* perm = ws + NROWS;

    k_len<<<NROWS / 4, 256, 0, stream>>>(vmask, lens);
    k_sort<<<1, 1024, 0, stream>>>(lens, perm);

    gru_fused<<<NGRP, 256, 0, stream>>>(actor_ids, action_ids, street_ids, bet,
                                        E_actor, E_action, E_street,
                                        W_proj, b_proj, W_ih, b_ih, W_hh, b_hh,
                                        perm, lens, out);
}

// Round 15
// 155.888 us; speedup vs baseline: 1.1923x; 1.0092x over previous
//
#include <hip/hip_runtime.h>

#define HID 64
#define TT  128
#define NROWS 8192
#define NGRP (NROWS / 8)    // 1024 blocks of 8 rows; 4 blocks/CU
#define LOG2E 1.44269504088896f

typedef _Float16 half8 __attribute__((ext_vector_type(8)));
typedef __fp16   fp16x2 __attribute__((ext_vector_type(2)));
typedef float    f32x4 __attribute__((ext_vector_type(4)));

// ---------- pre-pass: length-sort rows into balanced 8-row groups ----------
// ws layout (ints): lens[8192] | perm[8192]

__global__ void k_len(const int* __restrict__ mask, int* __restrict__ lens) {
    const int row = blockIdx.x * 4 + (threadIdx.x >> 6);
    const int l   = threadIdx.x & 63;
    const int* mrow = mask + row * TT;
    int c = (mrow[l] != 0) + (mrow[l + 64] != 0);
    #pragma unroll
    for (int k = 32; k >= 1; k >>= 1) c += __shfl_xor(c, k);
    if (l == 0) lens[row] = c;
}

// Single block: LDS histogram -> prefix -> scatter. Descending rank d ->
// 8-row group g8 = d/8; slots {c, 511-c, 512+c, 1023-c} land on CU c.
__global__ __launch_bounds__(1024) void k_sort(const int* __restrict__ lens,
                                               int* __restrict__ perm) {
    __shared__ int hist[TT + 1];
    __shared__ int offs[TT + 1];
    const int tid = threadIdx.x;
    if (tid <= TT) hist[tid] = 0;
    __syncthreads();
    int myL[8];
    #pragma unroll
    for (int i = 0; i < 8; i++) {
        myL[i] = lens[tid + 1024 * i];
        atomicAdd(&hist[myL[i]], 1);
    }
    __syncthreads();
    if (tid <= TT) {
        int s = 0;
        for (int j = 0; j < tid; j++) s += hist[j];
        offs[tid] = s;
    }
    __syncthreads();
    #pragma unroll
    for (int i = 0; i < 8; i++) {
        const int pos = atomicAdd(&offs[myL[i]], 1);      // ascending rank
        const int d   = NROWS - 1 - pos;                  // descending rank
        const int g8  = d >> 3, r = d & 7;
        int b;
        if      (g8 < 256) b = g8;
        else if (g8 < 512) b = 256 + (511 - g8);
        else if (g8 < 768) b = 512 + (g8 - 512);
        else               b = 768 + (1023 - g8);
        perm[b * 8 + r] = tid + 1024 * i;
    }
}

// ---------- main GRU: R10 + cvt_pkrtz pack + single embl + setprio ----------
// 8-row blocks, cols 0-7 rows / 8-15 dups; lane hf=cc>>3 activates e-pair.
__global__ __launch_bounds__(256, 4) void gru_fused(
    const int* __restrict__ actor_ids, const int* __restrict__ action_ids,
    const int* __restrict__ street_ids, const float* __restrict__ bet,
    const float* __restrict__ E_actor, const float* __restrict__ E_action,
    const float* __restrict__ E_street, const float* __restrict__ W_proj,
    const float* __restrict__ b_proj, const float* __restrict__ W_ih,
    const float* __restrict__ b_ih, const float* __restrict__ W_hh,
    const float* __restrict__ b_hh, const int* __restrict__ perm,
    const int* __restrict__ lens, float* __restrict__ out)
{
    __shared__ __align__(16) union {
        float wfs[192][32];                           // startup: fused W_f (scaled)
        struct {
            int pb[TT][9];                            // ids|bet16, 8 rows + pad
            __align__(16) _Float16 hb[2][8][72];      // h f16 dbuf, stride 72
            int Lsh[8];
            int Psh[8];
        } c;
    } A;
    __shared__ __align__(16) _Float16 embl[144];      // single copy (R10's 8x
                                                      // replication raised conflicts)
    __shared__ float bfs[192];                        // raw fused bias b_f

    const int tid = threadIdx.x;
    const int wv  = tid >> 6;        // wave = hid quarter (j-split)
    const int l   = tid & 63;
    const int q   = l >> 4;          // k-quad / j-subquad
    const int cc  = l & 15;          // MFMA col
    const int cr  = cc & 7;          // batch row within group
    const int hf  = cc >> 3;         // activation element half
    const int g   = blockIdx.x;

    // embedding rows: 0..6 actor, 7..10 action, 11..15 street(+pad), 16 zero
    for (int i = tid; i < 136; i += 256) {
        int r = i >> 3, m = i & 7;
        float v = 0.f;
        if (r < 7)       v = E_actor[r * 8 + m];
        else if (r < 11) v = E_action[(r - 7) * 8 + m];
        else if (r < 16) v = (m < 4) ? E_street[(r - 11) * 4 + m] : 0.f;
        embl[i] = (_Float16)v;
    }

    // ---- startup: fused input weights into LDS ----
    if (tid < 192) {
        const int j = tid;
        float wf[21];
        #pragma unroll
        for (int m = 0; m < 21; m++) wf[m] = 0.f;
        float bf = b_ih[j];
        for (int k = 0; k < 32; k++) {
            const float w = W_ih[j * 32 + k];
            bf += w * b_proj[k];
            #pragma unroll
            for (int m = 0; m < 21; m++) wf[m] += w * W_proj[k * 21 + m];
        }
        const float s = (j < 128) ? LOG2E : 2.f * LOG2E;
        #pragma unroll
        for (int m = 0; m < 21; m++) A.wfs[j][m] = wf[m] * s;
        #pragma unroll
        for (int m = 21; m < 32; m++) A.wfs[j][m] = 0.f;
        bfs[j] = bf;
    }
    __syncthreads();

    // ---- extract per-lane A-fragments + biases (registers) ----
    half8 Af[3], Ah[3][2];
    {
        const int m16 = l & 15, kq = l >> 4;
        #pragma unroll
        for (int g3 = 0; g3 < 3; g3++) {
            const int jr = g3 * 64 + wv * 16 + m16;
            _Float16 v[8];
            #pragma unroll
            for (int m = 0; m < 8; m++) v[m] = (_Float16)A.wfs[jr][kq * 8 + m];
            Af[g3] = *(half8*)v;
            const float s = (g3 < 2) ? LOG2E : 2.f * LOG2E;
            #pragma unroll
            for (int kt = 0; kt < 2; kt++) {
                _Float16 w[8];
                #pragma unroll
                for (int m = 0; m < 8; m++)
                    w[m] = (_Float16)(W_hh[jr * HID + kt * 32 + kq * 8 + m] * s);
                Ah[g3][kt] = *(half8*)w;
            }
        }
    }
    f32x4 biasR, biasZ, biasX, biasH;
    #pragma unroll
    for (int e = 0; e < 4; e++) {
        const int idx = 16 * wv + 4 * q + e;
        biasR[e] = (bfs[idx]      + b_hh[idx])      * LOG2E;
        biasZ[e] = (bfs[64 + idx] + b_hh[64 + idx]) * LOG2E;
        biasX[e] = bfs[128 + idx]  * (2.f * LOG2E);
        biasH[e] = b_hh[128 + idx] * (2.f * LOG2E);
    }
    __syncthreads();   // wfs dead; arena becomes pb/hb

    // ---- stage pb via perm (32 thr/row), zero hb, fetch lengths ----
    for (int i = tid; i < 2 * 8 * 72 / 2; i += 256) ((int*)A.c.hb)[i] = 0;
    {
        const int r = tid >> 5, tl = tid & 31;
        const int prow = perm[g * 8 + r];
        const int base = prow * TT;
        #pragma unroll
        for (int i = 0; i < 4; i++) {
            const int t = tl + 32 * i;
            const int a = actor_ids[base + t], c = action_ids[base + t];
            const int s = street_ids[base + t];
            const _Float16 f16 = (_Float16)bet[base + t];
            const unsigned fb = (unsigned)*(const unsigned short*)&f16;
            A.c.pb[t][r] = (int)(a | (c << 3) | (s << 5) | (fb << 16));
        }
        if (tl == 0) { A.c.Lsh[r] = lens[prow]; A.c.Psh[r] = prow; }
    }
    __syncthreads();

    const int Ln = A.c.Lsh[cr];
    int Lmax = Ln;
    { int o = __shfl_xor(Lmax, 1); Lmax = o > Lmax ? o : Lmax; }
    { int o = __shfl_xor(Lmax, 2); Lmax = o > Lmax ? o : Lmax; }
    { int o = __shfl_xor(Lmax, 4); Lmax = o > Lmax ? o : Lmax; }

    const bool isq2 = (q == 2);
    const int sh = (q == 1) ? 3 : (q == 2) ? 5 : 0;
    const int mk = (q == 1) ? 3 : (q == 3) ? 0 : 7;
    const int of = (q == 1) ? 7 : (q == 2) ? 11 : (q == 3) ? 16 : 0;

    const int j0 = 16 * wv + 4 * q + 2 * hf;
    float h0 = 0.f, h1 = 0.f;
    const f32x4 zero4 = {0.f, 0.f, 0.f, 0.f};

    // ---- prologue: Bf(0), Bf(1); x(0) ----
    half8 BfA, BfB;
    {
        const int p0 = A.c.pb[0][cr];
        BfA = *(const half8*)&embl[(((p0 >> sh) & mk) + of) * 8];
        uint4* b0 = (uint4*)&BfA;
        b0->z = isq2 ? ((unsigned)p0 >> 16) : b0->z;   // {bet16, 0} at k=20,21
        const int p1 = A.c.pb[1][cr];
        BfB = *(const half8*)&embl[(((p1 >> sh) & mk) + of) * 8];
        uint4* b1 = (uint4*)&BfB;
        b1->z = isq2 ? ((unsigned)p1 >> 16) : b1->z;
    }
    f32x4 xR0 = __builtin_amdgcn_mfma_f32_16x16x32_f16(Af[0], BfA, biasR, 0, 0, 0);
    f32x4 xZ0 = __builtin_amdgcn_mfma_f32_16x16x32_f16(Af[1], BfA, biasZ, 0, 0, 0);
    f32x4 xX0 = __builtin_amdgcn_mfma_f32_16x16x32_f16(Af[2], BfA, biasX, 0, 0, 0);
    f32x4 xR1, xZ1, xX1;

    // activation macro: consumes aR,aZ,aH,aX; updates h0,h1; writes hb[WB]
    #define ACT_WRITE(aR_, aZ_, aH_, aX_, LIVE_, WB_)                              \
    {                                                                              \
        const float vR0 = hf ? aR_[2] : aR_[0], vR1 = hf ? aR_[3] : aR_[1];        \
        const float vZ0 = hf ? aZ_[2] : aZ_[0], vZ1 = hf ? aZ_[3] : aZ_[1];        \
        const float vH0 = hf ? aH_[2] : aH_[0], vH1 = hf ? aH_[3] : aH_[1];        \
        const float vX0 = hf ? aX_[2] : aX_[0], vX1 = hf ? aX_[3] : aX_[1];        \
        const float r0 = __builtin_amdgcn_rcpf(1.f + __builtin_amdgcn_exp2f(-vR0));\
        const float z0 = __builtin_amdgcn_rcpf(1.f + __builtin_amdgcn_exp2f(-vZ0));\
        const float y0 = vX0 + r0 * vH0;                                           \
        const float n0 = 1.f - 2.f * __builtin_amdgcn_rcpf(1.f + __builtin_amdgcn_exp2f(y0)); \
        const float hv0 = n0 + z0 * (h0 - n0);                                     \
        h0 = (LIVE_) ? hv0 : h0;                                                   \
        const float r1 = __builtin_amdgcn_rcpf(1.f + __builtin_amdgcn_exp2f(-vR1));\
        const float z1 = __builtin_amdgcn_rcpf(1.f + __builtin_amdgcn_exp2f(-vZ1));\
        const float y1 = vX1 + r1 * vH1;                                           \
        const float n1 = 1.f - 2.f * __builtin_amdgcn_rcpf(1.f + __builtin_amdgcn_exp2f(y1)); \
        const float hv1 = n1 + z1 * (h1 - n1);                                     \
        h1 = (LIVE_) ? hv1 : h1;                                                   \
        const fp16x2 pk2 = __builtin_amdgcn_cvt_pkrtz(h0, h1);                     \
        *(unsigned*)&A.c.hb[WB_][cr][j0] = __builtin_bit_cast(unsigned, pk2);      \
    }

    for (int t = 0; t < Lmax; t += 2) {
        // ======== step A (even t): read hb[0], write hb[1] ========
        {
            const half8 Bh0 = *(const half8*)&A.c.hb[0][cr][q * 8];
            const half8 Bh1 = *(const half8*)&A.c.hb[0][cr][32 + q * 8];
            const int t2 = (t + 2 < TT) ? t + 2 : TT - 1;
            const int p2 = A.c.pb[t2][cr];

            __builtin_amdgcn_s_setprio(1);
            f32x4 aRa = __builtin_amdgcn_mfma_f32_16x16x32_f16(Ah[0][0], Bh0, xR0, 0, 0, 0);
            f32x4 aRb = __builtin_amdgcn_mfma_f32_16x16x32_f16(Ah[0][1], Bh1, zero4, 0, 0, 0);
            f32x4 aZ = __builtin_amdgcn_mfma_f32_16x16x32_f16(Ah[1][0], Bh0, xZ0, 0, 0, 0);
            aZ = __builtin_amdgcn_mfma_f32_16x16x32_f16(Ah[1][1], Bh1, aZ, 0, 0, 0);
            f32x4 aH = __builtin_amdgcn_mfma_f32_16x16x32_f16(Ah[2][0], Bh0, biasH, 0, 0, 0);
            aH = __builtin_amdgcn_mfma_f32_16x16x32_f16(Ah[2][1], Bh1, aH, 0, 0, 0);
            const f32x4 aR = aRa + aRb;

            // x(t+1) from BfB (register-only B)
            xR1 = __builtin_amdgcn_mfma_f32_16x16x32_f16(Af[0], BfB, biasR, 0, 0, 0);
            xZ1 = __builtin_amdgcn_mfma_f32_16x16x32_f16(Af[1], BfB, biasZ, 0, 0, 0);
            xX1 = __builtin_amdgcn_mfma_f32_16x16x32_f16(Af[2], BfB, biasX, 0, 0, 0);

            // gather Bf(t+2) -> BfA (old BfA already consumed)
            BfA = *(const half8*)&embl[(((p2 >> sh) & mk) + of) * 8];
            uint4* bq = (uint4*)&BfA;
            bq->z = isq2 ? ((unsigned)p2 >> 16) : bq->z;

            ACT_WRITE(aR, aZ, aH, xX0, t < Ln, 1);
            __builtin_amdgcn_s_setprio(0);
        }
        __syncthreads();
        // ======== step B (t+1): read hb[1], write hb[0] ========
        {
            const half8 Bh0 = *(const half8*)&A.c.hb[1][cr][q * 8];
            const half8 Bh1 = *(const half8*)&A.c.hb[1][cr][32 + q * 8];
            const int t3 = (t + 3 < TT) ? t + 3 : TT - 1;
            const int p3 = A.c.pb[t3][cr];

            __builtin_amdgcn_s_setprio(1);
            f32x4 aRa = __builtin_amdgcn_mfma_f32_16x16x32_f16(Ah[0][0], Bh0, xR1, 0, 0, 0);
            f32x4 aRb = __builtin_amdgcn_mfma_f32_16x16x32_f16(Ah[0][1], Bh1, zero4, 0, 0, 0);
            f32x4 aZ = __builtin_amdgcn_mfma_f32_16x16x32_f16(Ah[1][0], Bh0, xZ1, 0, 0, 0);
            aZ = __builtin_amdgcn_mfma_f32_16x16x32_f16(Ah[1][1], Bh1, aZ, 0, 0, 0);
            f32x4 aH = __builtin_amdgcn_mfma_f32_16x16x32_f16(Ah[2][0], Bh0, biasH, 0, 0, 0);
            aH = __builtin_amdgcn_mfma_f32_16x16x32_f16(Ah[2][1], Bh1, aH, 0, 0, 0);
            const f32x4 aR = aRa + aRb;

            // x(t+2) from BfA (just gathered)
            xR0 = __builtin_amdgcn_mfma_f32_16x16x32_f16(Af[0], BfA, biasR, 0, 0, 0);
            xZ0 = __builtin_amdgcn_mfma_f32_16x16x32_f16(Af[1], BfA, biasZ, 0, 0, 0);
            xX0 = __builtin_amdgcn_mfma_f32_16x16x32_f16(Af[2], BfA, biasX, 0, 0, 0);

            // gather Bf(t+3) -> BfB
            BfB = *(const half8*)&embl[(((p3 >> sh) & mk) + of) * 8];
            uint4* bq = (uint4*)&BfB;
            bq->z = isq2 ? ((unsigned)p3 >> 16) : bq->z;

            ACT_WRITE(aR, aZ, aH, xX1, t + 1 < Ln, 0);
            __builtin_amdgcn_s_setprio(0);
        }
        __syncthreads();
    }
    #undef ACT_WRITE

    const int prow = A.c.Psh[cr];
    *(float2*)&out[prow * HID + j0] = make_float2(h0, h1);
}

extern "C" void kernel_launch(void* const* d_in, const int* in_sizes, int n_in,
                              void* d_out, int out_size, void* d_ws, size_t ws_size,
                              hipStream_t stream) {
    const int*   actor_ids  = (const int*)d_in[0];
    const int*   action_ids = (const int*)d_in[1];
    const int*   street_ids = (const int*)d_in[2];
    const float* bet        = (const float*)d_in[3];
    const int*   vmask      = (const int*)d_in[4];
    const float* E_actor    = (const float*)d_in[5];
    const float* E_action   = (const float*)d_in[6];
    const float* E_street   = (const float*)d_in[7];
    const float* W_proj     = (const float*)d_in[8];
    const float* b_proj     = (const float*)d_in[9];
    const float* W_ih       = (const float*)d_in[10];
    const float* W_hh       = (const float*)d_in[11];
    const float* b_ih       = (const float*)d_in[12];
    const float* b_hh       = (const float*)d_in[13];
    float*       out        = (float*)d_out;

    int* ws   = (int*)d_ws;
    int* lens = ws;
    int* perm = ws + NROWS;

    k_len<<<NROWS / 4, 256, 0, stream>>>(vmask, lens);
    k_sort<<<1, 1024, 0, stream>>>(lens, perm);

    gru_fused<<<NGRP, 256, 0, stream>>>(actor_ids, action_ids, street_ids, bet,
                                        E_actor, E_action, E_street,
                                        W_proj, b_proj, W_ih, b_ih, W_hh, b_hh,
                                        perm, lens, out);
}